// Round 1
// baseline (210.284 us; speedup 1.0000x reference)
//
#include <hip/hip_runtime.h>

#define N_PP   8192
#define N_A    8192
#define DIM    16
#define NEDGE  262144
#define J_TILE 1024
#define I_TILE 128
#define TPB    256

// ws layout (floats): [0]=nonlink_pp  [1]=link_pp  [2]=nonlink_ap  [3]=link_ap

__global__ void zero_ws_kernel(float* __restrict__ ws) {
    if (threadIdx.x < 4) ws[threadIdx.x] = 0.0f;
}

__device__ __forceinline__ float waveReduce(float v) {
#pragma unroll
    for (int off = 32; off > 0; off >>= 1)
        v += __shfl_down(v, off, 64);
    return v;
}

// z==0: pp matrix (rows=p_star, cols=p, bias=gamma, strict upper triangle j>i)
// z==1: ap matrix (rows=p_star, cols=a, bias=beta, full sum)
__global__ __launch_bounds__(TPB) void matrix_kernel(
    const float* __restrict__ p_star, const float* __restrict__ p,
    const float* __restrict__ a, const float* __restrict__ beta_ap,
    const float* __restrict__ gamma_pp, float* __restrict__ ws)
{
    const bool isPP = (blockIdx.z == 0);
    const int j0 = blockIdx.x * J_TILE;
    const int i0 = blockIdx.y * I_TILE;
    // whole tile has j <= i  ->  strict-upper-triangle contribution is empty
    if (isPP && (j0 + J_TILE - 1) <= i0) return;

    const float* __restrict__ Y  = isPP ? p : a;
    const float* __restrict__ rB = isPP ? gamma_pp : beta_ap;          // row bias [i]
    const float* __restrict__ cB = (isPP ? gamma_pp : beta_ap) + N_PP; // col bias [j]

    __shared__ float4 rowrec[I_TILE * 5];   // per row: x(4xfloat4), {|x|^2, bias, -, -}
    __shared__ float  smred[TPB / 64];

    for (int r = threadIdx.x; r < I_TILE; r += TPB) {
        const float4* xp = (const float4*)(p_star + (size_t)(i0 + r) * DIM);
        float4 x0 = xp[0], x1 = xp[1], x2 = xp[2], x3 = xp[3];
        float xx = x0.x*x0.x + x0.y*x0.y + x0.z*x0.z + x0.w*x0.w
                 + x1.x*x1.x + x1.y*x1.y + x1.z*x1.z + x1.w*x1.w
                 + x2.x*x2.x + x2.y*x2.y + x2.z*x2.z + x2.w*x2.w
                 + x3.x*x3.x + x3.y*x3.y + x3.z*x3.z + x3.w*x3.w;
        rowrec[r*5+0] = x0; rowrec[r*5+1] = x1;
        rowrec[r*5+2] = x2; rowrec[r*5+3] = x3;
        rowrec[r*5+4] = make_float4(xx, rB[i0 + r], 0.f, 0.f);
    }
    __syncthreads();

    const int jt = j0 + (int)threadIdx.x;   // thread's column c: jt + c*256
    float4 y[4][4];
    float  y2[4], cb[4];
#pragma unroll
    for (int c = 0; c < 4; ++c) {
        const float4* yp = (const float4*)(Y + (size_t)(jt + c*256) * DIM);
        float4 a0 = yp[0], a1 = yp[1], a2 = yp[2], a3 = yp[3];
        y[c][0] = a0; y[c][1] = a1; y[c][2] = a2; y[c][3] = a3;
        y2[c] = a0.x*a0.x + a0.y*a0.y + a0.z*a0.z + a0.w*a0.w
              + a1.x*a1.x + a1.y*a1.y + a1.z*a1.z + a1.w*a1.w
              + a2.x*a2.x + a2.y*a2.y + a2.z*a2.z + a2.w*a2.w
              + a3.x*a3.x + a3.y*a3.y + a3.z*a3.z + a3.w*a3.w;
        cb[c] = cB[jt + c*256];
    }

    float acc[4] = {0.f, 0.f, 0.f, 0.f};
    for (int r = 0; r < I_TILE; ++r) {
        float4 x0 = rowrec[r*5+0], x1 = rowrec[r*5+1],
               x2 = rowrec[r*5+2], x3 = rowrec[r*5+3];
        float4 meta = rowrec[r*5+4];
        const int i = i0 + r;
#pragma unroll
        for (int c = 0; c < 4; ++c) {
            float dot = x0.x*y[c][0].x + x0.y*y[c][0].y + x0.z*y[c][0].z + x0.w*y[c][0].w
                      + x1.x*y[c][1].x + x1.y*y[c][1].y + x1.z*y[c][1].z + x1.w*y[c][1].w
                      + x2.x*y[c][2].x + x2.y*y[c][2].y + x2.z*y[c][2].z + x2.w*y[c][2].w
                      + x3.x*y[c][3].x + x3.y*y[c][3].y + x3.z*y[c][3].z + x3.w*y[c][3].w;
            float d2 = fmaxf(fmaf(-2.f, dot, meta.x + y2[c]), 0.f);
            float t  = __expf(meta.y + cb[c] - __builtin_amdgcn_sqrtf(d2));
            if (isPP && (jt + (c << 8)) <= i) t = 0.f;   // strict upper triangle
            acc[c] += t;
        }
    }

    float v = waveReduce(acc[0] + acc[1] + acc[2] + acc[3]);
    if ((threadIdx.x & 63) == 0) smred[threadIdx.x >> 6] = v;
    __syncthreads();
    if (threadIdx.x == 0)
        atomicAdd(&ws[isPP ? 0 : 2], smred[0] + smred[1] + smred[2] + smred[3]);
}

// y==0: pp edges -> ws[1]; y==1: ap edges -> ws[3]
__global__ __launch_bounds__(TPB) void edge_kernel(
    const float* __restrict__ p_star, const float* __restrict__ p,
    const float* __restrict__ a, const float* __restrict__ beta_ap,
    const float* __restrict__ gamma_pp, const int* __restrict__ edges_pp,
    const int* __restrict__ edges_ap, float* __restrict__ ws)
{
    __shared__ float smred[TPB / 64];
    const bool isPP = (blockIdx.y == 0);
    const int e = blockIdx.x * TPB + threadIdx.x;   // grid sized exactly to NEDGE

    const float* yrow;
    float bias;
    int e0;
    if (isPP) {
        e0 = edges_pp[e];
        int e1 = edges_pp[NEDGE + e];
        yrow = p + (size_t)e1 * DIM;
        bias = gamma_pp[e0] + gamma_pp[N_PP + e1];
    } else {
        e0 = edges_ap[e];
        int e1 = edges_ap[NEDGE + e];          // in [N_PP, N_PP+N_A)
        yrow = a + (size_t)(e1 - N_PP) * DIM;
        bias = beta_ap[e0] + beta_ap[e1];
    }
    const float4* xp = (const float4*)(p_star + (size_t)e0 * DIM);
    const float4* yp = (const float4*)yrow;
    float d2 = 0.f;
#pragma unroll
    for (int k = 0; k < 4; ++k) {
        float4 xv = xp[k], yv = yp[k];
        float dx = xv.x - yv.x, dy = xv.y - yv.y, dz = xv.z - yv.z, dw = xv.w - yv.w;
        d2 += dx*dx + dy*dy + dz*dz + dw*dw;
    }
    float v = bias - __builtin_amdgcn_sqrtf(d2);

    float s = waveReduce(v);
    if ((threadIdx.x & 63) == 0) smred[threadIdx.x >> 6] = s;
    __syncthreads();
    if (threadIdx.x == 0)
        atomicAdd(&ws[isPP ? 1 : 3], smred[0] + smred[1] + smred[2] + smred[3]);
}

__global__ void finalize_kernel(const float* __restrict__ ws, float* __restrict__ out) {
    // nll_pp = nonlink_pp - link_pp ; nll_ap = nonlink_ap - link_ap
    out[0] = 0.5f * (ws[0] - ws[1]) / (float)N_PP
           + 0.5f * (ws[2] - ws[3]) / (float)N_A;
}

extern "C" void kernel_launch(void* const* d_in, const int* in_sizes, int n_in,
                              void* d_out, int out_size, void* d_ws, size_t ws_size,
                              hipStream_t stream) {
    const float* p_star   = (const float*)d_in[0];
    const float* p        = (const float*)d_in[1];
    const float* a        = (const float*)d_in[2];
    const float* beta_ap  = (const float*)d_in[3];
    const float* gamma_pp = (const float*)d_in[4];
    const int*   edges_pp = (const int*)d_in[5];
    const int*   edges_ap = (const int*)d_in[6];
    // d_in[7..9] are identity arange node lists (p_star_nodes, p_nodes, a_nodes)

    float* ws  = (float*)d_ws;
    float* out = (float*)d_out;

    hipLaunchKernelGGL(zero_ws_kernel, dim3(1), dim3(64), 0, stream, ws);
    hipLaunchKernelGGL(matrix_kernel,
                       dim3(N_A / J_TILE, N_PP / I_TILE, 2), dim3(TPB), 0, stream,
                       p_star, p, a, beta_ap, gamma_pp, ws);
    hipLaunchKernelGGL(edge_kernel,
                       dim3(NEDGE / TPB, 2), dim3(TPB), 0, stream,
                       p_star, p, a, beta_ap, gamma_pp, edges_pp, edges_ap, ws);
    hipLaunchKernelGGL(finalize_kernel, dim3(1), dim3(1), 0, stream, ws, out);
}